// Round 14
// baseline (108.897 us; speedup 1.0000x reference)
//
#include <hip/hip_runtime.h>

#define HH 80
#define WW 80
#define BB 8
#define CIN 128
#define C2 256
#define MID 64
#define OFFC 72
#define NG 4
#define CG 32
#define HW (HH * WW)
#define PD 82           // padded spatial dim
#define PP (PD * PD)    // padded pixels per image
#define STP 72          // conv LDS px stride in channels
#define QSTRIDE 493     // deform LDS plane stride in 16B units

typedef short bf16x8 __attribute__((ext_vector_type(8)));
typedef float f32x4  __attribute__((ext_vector_type(4)));

static __device__ __forceinline__ unsigned short f2bf(float f) {
    union { float f; unsigned u; } v; v.f = f;
    unsigned r = v.u + 0x7fffu + ((v.u >> 16) & 1u);   // RNE
    return (unsigned short)(r >> 16);
}

// ---------------- prep: weight packs + borders + rgbc pack (one kernel) -------
__global__ __launch_bounds__(512) void prep_kernel(
    const float* __restrict__ w1, const float* __restrict__ w2,
    const float* __restrict__ dw, const float* __restrict__ rgb,
    const float* __restrict__ thermal,
    unsigned short* __restrict__ w1F, unsigned short* __restrict__ w2F,
    unsigned short* __restrict__ dwF,
    unsigned short* __restrict__ rgbcp, unsigned short* __restrict__ hdnp)
{
    if (blockIdx.x < 450) {
        int idx = blockIdx.x * 512 + threadIdx.x;
        if (idx < 147456) {
            int e  = idx & 7;
            int t1 = idx >> 3;  int l  = t1 & 63;
            int t2 = t1 >> 6;   int cb = t2 & 1;
            int t3 = t2 >> 1;   int tap = t3 % 9;
            int t4 = t3 / 9;    int cc = t4 & 3;  int nf = t4 >> 2;
            int oc = nf * 16 + (l & 15);
            int ic = cc * 64 + cb * 32 + (l >> 4) * 8 + e;
            w1F[idx] = f2bf(w1[((size_t)oc * C2 + ic) * 9 + tap]);
        } else if (idx < 193536) {
            int i2 = idx - 147456;
            int e  = i2 & 7;
            int t1 = i2 >> 3;  int l  = t1 & 63;
            int t2 = t1 >> 6;  int cb = t2 & 1;
            int t3 = t2 >> 1;  int tap = t3 % 9;
            int nf = t3 / 9;
            int oc = nf * 16 + (l & 15);
            int ic = cb * 32 + (l >> 4) * 8 + e;
            float v = (oc < OFFC) ? w2[((size_t)oc * MID + ic) * 9 + tap] : 0.f;
            w2F[i2] = f2bf(v);
        } else {
            int i3 = idx - 193536;
            int e   = i3 & 7;
            int l   = (i3 >> 3) & 63;
            int ocb = (i3 >> 9) & 1;
            int gt  = i3 >> 10;
            int tap = gt % 9, g = gt / 9;
            int oc = ocb * 16 + (l & 15);
            int c  = (l >> 4) * 8 + e;
            dwF[i3] = f2bf(dw[((size_t)(g * CG + oc) * CG + c) * 9 + tap]);
        }
    } else if (blockIdx.x < 458) {
        int idx = (blockIdx.x - 450) * 512 + threadIdx.x;
        if (idx >= BB * 324) return;
        int b = idx / 324, e = idx - (idx / 324) * 324;
        int y, x;
        if (e < 82)       { y = 0;  x = e; }
        else if (e < 164) { y = 81; x = e - 82; }
        else if (e < 244) { y = e - 164 + 1; x = 0; }
        else              { y = e - 244 + 1; x = 81; }
        size_t pos = (size_t)b * PP + y * PD + x;
        uint4 z = {0, 0, 0, 0};
        uint4* r = (uint4*)(rgbcp + pos * C2);
        #pragma unroll
        for (int i = 0; i < 32; ++i) r[i] = z;
        uint4* h = (uint4*)(hdnp + pos * MID);
        #pragma unroll
        for (int i = 0; i < 8; ++i) h[i] = z;
    } else {
        const int pb = blockIdx.x - 458;      // 0..639
        const int b = pb & 7, y = pb >> 3;
        __shared__ unsigned tile[128 * 84];   // [ch-pair][px], 43 KB

        for (int e = threadIdx.x; e < 128 * 20; e += 512) {
            int c2 = e / 20, p4 = e - c2 * 20;
            int ch0 = 2 * c2;
            const float* srcA = (ch0 < CIN)
                ? rgb     + ((size_t)(b * CIN + ch0)       * HH + y) * WW
                : thermal + ((size_t)(b * CIN + ch0 - CIN) * HH + y) * WW;
            float4 a0 = *(const float4*)(srcA + p4 * 4);
            float4 a1 = *(const float4*)(srcA + HW + p4 * 4);
            unsigned w0 = f2bf(a0.x) | ((unsigned)f2bf(a1.x) << 16);
            unsigned w1r = f2bf(a0.y) | ((unsigned)f2bf(a1.y) << 16);
            unsigned w2r = f2bf(a0.z) | ((unsigned)f2bf(a1.z) << 16);
            unsigned w3 = f2bf(a0.w) | ((unsigned)f2bf(a1.w) << 16);
            uint4 v = {w0, w1r, w2r, w3};
            *(uint4*)&tile[c2 * 84 + p4 * 4] = v;
        }
        __syncthreads();

        for (int e = threadIdx.x; e < 80 * 64; e += 512) {
            int px = e >> 6, c4 = e & 63;
            uint2 v;
            v.x = tile[(2 * c4) * 84 + px];
            v.y = tile[(2 * c4 + 1) * 84 + px];
            *(uint2*)(rgbcp + ((size_t)b * PP + (size_t)(y + 1) * PD + px + 1) * C2 + c4 * 4) = v;
        }
    }
}

// ---------------- conv1: implicit GEMM; wave = 32 oc x mf-half ---------------
// grid: B*H (b = bid&7); block 256 = 4 waves: och = wv&1, mh = wv>>1.
// Each af LDS read feeds 2 MFMAs (two oc fragments) -> af traffic halved.
__global__ __launch_bounds__(256) void conv1_mfma(
    const unsigned short* __restrict__ rgbcp, const unsigned short* __restrict__ w1F,
    const float* __restrict__ b1, unsigned short* __restrict__ hdnp)
{
    const int by = blockIdx.x;
    const int b = by & 7, y = by >> 3;
    const int tid = threadIdx.x;
    const int wv = tid >> 6;
    const int och = wv & 1;          // oc block: nf = 2*och, 2*och+1
    const int mh  = wv >> 1;         // mf half: 0 -> {0,1,2}, 1 -> {3,4}
    const int mf0 = mh ? 3 : 0;
    const int nmf = mh ? 2 : 3;
    const int l = tid & 63, l15 = l & 15, lk = l >> 4;

    __shared__ __align__(16) unsigned short st[3 * 82 * STP];   // 35.4 KB

    f32x4 acc[2][3];
    #pragma unroll
    for (int j = 0; j < 2; ++j)
        #pragma unroll
        for (int i = 0; i < 3; ++i) acc[j][i] = (f32x4){0.f, 0.f, 0.f, 0.f};

    const size_t rowbase = (size_t)b * PP + (size_t)y * PD;   // padded rows y..y+2

    for (int cc = 0; cc < 4; ++cc) {
        __syncthreads();
        for (int e = tid; e < 3 * 82 * 8; e += 256) {
            int r   = e / 656;
            int rem = e - r * 656;
            int px  = rem >> 3;
            int c8  = rem & 7;
            const uint4 v = *(const uint4*)(rgbcp + (rowbase + (size_t)r * PD + px) * C2 + cc * 64 + c8 * 8);
            *(uint4*)&st[(r * 82 + px) * STP + c8 * 8] = v;
        }
        __syncthreads();

        const unsigned short* bwA = w1F + (((size_t)((2 * och)     * 4 + cc) * 9) * 2 * 64) * 8;
        const unsigned short* bwB = w1F + (((size_t)((2 * och + 1) * 4 + cc) * 9) * 2 * 64) * 8;
        #pragma unroll
        for (int tap = 0; tap < 9; ++tap) {
            const int ky = tap / 3, kx = tap - ky * 3;
            #pragma unroll
            for (int cb = 0; cb < 2; ++cb) {
                bf16x8 bfA = *(const bf16x8*)(bwA + ((size_t)(tap * 2 + cb) * 64 + l) * 8);
                bf16x8 bfB = *(const bf16x8*)(bwB + ((size_t)(tap * 2 + cb) * 64 + l) * 8);
                #pragma unroll
                for (int mi = 0; mi < 3; ++mi) {
                    if (mi < nmf) {
                        const int mf = mf0 + mi;
                        bf16x8 af = *(const bf16x8*)&st[(ky * 82 + mf * 16 + l15 + kx) * STP + cb * 32 + lk * 8];
                        acc[0][mi] = __builtin_amdgcn_mfma_f32_16x16x32_bf16(af, bfA, acc[0][mi], 0, 0, 0);
                        acc[1][mi] = __builtin_amdgcn_mfma_f32_16x16x32_bf16(af, bfB, acc[1][mi], 0, 0, 0);
                    }
                }
            }
        }
    }

    #pragma unroll
    for (int j = 0; j < 2; ++j) {
        const int oc = och * 32 + j * 16 + l15;
        const float bias = b1[oc];
        unsigned short* ob = hdnp + ((size_t)b * PP + (size_t)(y + 1) * PD + 1) * MID + oc;
        #pragma unroll
        for (int mi = 0; mi < 3; ++mi) {
            if (mi < nmf) {
                const int mf = mf0 + mi;
                #pragma unroll
                for (int r = 0; r < 4; ++r) {
                    float v = acc[j][mi][r] + bias;
                    v = v > 0.f ? v : 0.f;
                    ob[(size_t)(mf * 16 + lk * 4 + r) * MID] = f2bf(v);
                }
            }
        }
    }
}

// ---------------- conv2: implicit GEMM, LDS-staged A, frag-packed B ----------
// grid: B*H (b = bid&7); block 320 = 5 waves (nf = 16 oc of 80 padded)
__global__ __launch_bounds__(320) void conv2_mfma(
    const unsigned short* __restrict__ hdnp, const unsigned short* __restrict__ w2F,
    const float* __restrict__ b2, const float* __restrict__ scale_p,
    float* __restrict__ offs)
{
    const int by = blockIdx.x;
    const int b = by & 7, y = by >> 3;
    const int tid = threadIdx.x;
    const int nf = tid / 64;
    const int l = tid & 63, l15 = l & 15, lk = l >> 4;

    __shared__ __align__(16) unsigned short st[3 * 82 * STP];

    f32x4 acc[5];
    #pragma unroll
    for (int i = 0; i < 5; ++i) acc[i] = (f32x4){0.f, 0.f, 0.f, 0.f};

    const size_t rowbase = (size_t)b * PP + (size_t)y * PD;

    for (int e = tid; e < 3 * 82 * 8; e += 320) {
        int r   = e / 656;
        int rem = e - r * 656;
        int px  = rem >> 3;
        int c8  = rem & 7;
        const uint4 v = *(const uint4*)(hdnp + (rowbase + (size_t)r * PD + px) * MID + c8 * 8);
        *(uint4*)&st[(r * 82 + px) * STP + c8 * 8] = v;
    }
    __syncthreads();

    const unsigned short* bw = w2F + ((size_t)nf * 9 * 2 * 64) * 8;
    #pragma unroll
    for (int tap = 0; tap < 9; ++tap) {
        const int ky = tap / 3, kx = tap - ky * 3;
        #pragma unroll
        for (int cb = 0; cb < 2; ++cb) {
            bf16x8 bf = *(const bf16x8*)(bw + ((size_t)(tap * 2 + cb) * 64 + l) * 8);
            #pragma unroll
            for (int mf = 0; mf < 5; ++mf) {
                bf16x8 af = *(const bf16x8*)&st[(ky * 82 + mf * 16 + l15 + kx) * STP + cb * 32 + lk * 8];
                acc[mf] = __builtin_amdgcn_mfma_f32_16x16x32_bf16(af, bf, acc[mf], 0, 0, 0);
            }
        }
    }

    const int oc = nf * 16 + l15;
    if (oc < OFFC) {
        const float scale = scale_p[0];
        const float bias = b2[oc];
        float* ob = offs + ((size_t)b * OFFC + oc) * HW + y * WW;
        #pragma unroll
        for (int mf = 0; mf < 5; ++mf) {
            float4 v;
            v.x = (acc[mf][0] + bias) * scale;
            v.y = (acc[mf][1] + bias) * scale;
            v.z = (acc[mf][2] + bias) * scale;
            v.w = (acc[mf][3] + bias) * scale;
            *(float4*)(ob + mf * 16 + lk * 4) = v;
        }
    }
}

// ---------------- deformable conv 3x3: fp32 LDS window + pk-fma bilinear ------
__global__ __launch_bounds__(640) void deform_kernel(
    const unsigned short* __restrict__ rgbcp, const float* __restrict__ offs,
    const unsigned short* __restrict__ dwF, const float* __restrict__ db,
    float* __restrict__ out)
{
    const int b = blockIdx.x & 7;
    const int rem = blockIdx.x >> 3;      // 0..159 (y2 inner, g outer)
    const int y2 = rem % 40;
    const int g  = rem / 40;
    const int wv64 = threadIdx.x >> 6;    // 0..9
    const int h  = (wv64 >= 5) ? 1 : 0;   // row within pair
    const int wv = wv64 - h * 5;          // x-tile 0..4
    const int l = threadIdx.x & 63, l15 = l & 15, lk = l >> 4;

    const int y0 = y2 * 2;
    const int y  = y0 + h;
    const int x  = wv * 16 + l15;
    const int p  = y * WW + x;
    const int p0 = y * WW + wv * 16;
    const int r0 = min(max(y0 - 1, 0), PD - 6);    // staged padded rows r0..r0+5

    __shared__ __align__(16) float st[8 * QSTRIDE * 4];   // 63,104 B

    const unsigned short* gsrc = rgbcp + ((size_t)b * PP + (size_t)r0 * PD) * C2 + g * CG;
    for (int e = threadIdx.x; e < 6 * 82 * 4; e += 640) {
        int pix = e >> 2;
        int c8  = e & 3;
        int r   = pix / 82, px = pix - r * 82;
        uint4 v = *(const uint4*)(gsrc + ((size_t)r * PD + px) * C2 + c8 * 8);
        unsigned uu[4] = {v.x, v.y, v.z, v.w};
        float4 lo, hi;
        lo.x = __uint_as_float(uu[0] << 16); lo.y = __uint_as_float(uu[0] & 0xffff0000u);
        lo.z = __uint_as_float(uu[1] << 16); lo.w = __uint_as_float(uu[1] & 0xffff0000u);
        hi.x = __uint_as_float(uu[2] << 16); hi.y = __uint_as_float(uu[2] & 0xffff0000u);
        hi.z = __uint_as_float(uu[3] << 16); hi.w = __uint_as_float(uu[3] & 0xffff0000u);
        *(float4*)&st[((2 * c8)     * QSTRIDE + pix) * 4] = lo;
        *(float4*)&st[((2 * c8 + 1) * QSTRIDE + pix) * 4] = hi;
    }
    __syncthreads();

    const float* ob = offs + ((size_t)b * OFFC + g * 18) * HW + p;
    float sy[9], sx[9];
    #pragma unroll
    for (int t = 0; t < 9; ++t) {
        float offy = ob[(size_t)(2 * t) * HW];
        float offx = ob[(size_t)(2 * t + 1) * HW];
        sy[t] = (float)(y + t / 3 - 1) + offy;
        sx[t] = (float)(x + t % 3 - 1) + offx;
    }

    f32x4 acc0 = (f32x4){0.f, 0.f, 0.f, 0.f};
    f32x4 acc1 = (f32x4){0.f, 0.f, 0.f, 0.f};
    const unsigned short* gb = rgbcp + (size_t)b * PP * C2 + g * CG + lk * 8;
    const unsigned short* wg = dwF + (size_t)g * 9 * 2 * 64 * 8 + (size_t)l * 8;
    const float* stlo = &st[(2 * lk) * QSTRIDE * 4];
    const float* sthi = &st[(2 * lk + 1) * QSTRIDE * 4];

    #pragma unroll
    for (int t = 0; t < 9; ++t) {
        float fy = floorf(sy[t]), fx = floorf(sx[t]);
        int iy = (int)fy, ix = (int)fx;
        float wy = sy[t] - fy, wx = sx[t] - fx;

        float my0 = ((unsigned)iy       < HH) ? 1.f : 0.f;
        float my1 = ((unsigned)(iy + 1) < HH) ? 1.f : 0.f;
        float mx0 = ((unsigned)ix       < WW) ? 1.f : 0.f;
        float mx1 = ((unsigned)(ix + 1) < WW) ? 1.f : 0.f;
        float w00 = (1.f - wy) * (1.f - wx) * my0 * mx0;
        float w01 = (1.f - wy) * wx         * my0 * mx1;
        float w10 = wy * (1.f - wx)         * my1 * mx0;
        float w11 = wy * wx                 * my1 * mx1;

        int cy0 = min(max(iy, 0), HH - 1) + 1;
        int cy1 = min(max(iy + 1, 0), HH - 1) + 1;
        int cx0 = min(max(ix, 0), WW - 1) + 1;
        int cx1 = min(max(ix + 1, 0), WW - 1) + 1;

        f32x4 smlo = (f32x4){0.f, 0.f, 0.f, 0.f};
        f32x4 smhi = (f32x4){0.f, 0.f, 0.f, 0.f};

        if (cy0 >= r0 && cy1 <= r0 + 5) {
            const int i00 = ((cy0 - r0) * 82 + cx0) * 4;
            const int i01 = ((cy0 - r0) * 82 + cx1) * 4;
            const int i10 = ((cy1 - r0) * 82 + cx0) * 4;
            const int i11 = ((cy1 - r0) * 82 + cx1) * 4;
            f32x4 w00v = {w00, w00, w00, w00};
            f32x4 w01v = {w01, w01, w01, w01};
            f32x4 w10v = {w10, w10, w10, w10};
            f32x4 w11v = {w11, w11, w11, w11};
            smlo += *(const f32x4*)&stlo[i00] * w00v;
            smhi += *(const f32x4*)&sthi[i00] * w00v;
            smlo += *(const f32x4*)&stlo[i01] * w01v;
            smhi += *(const f32x4*)&sthi[i01] * w01v;
            smlo += *(const f32x4*)&stlo[i10] * w10v;
            smhi += *(const f32x4*)&sthi[i10] * w10v;
            smlo += *(const f32x4*)&stlo[i11] * w11v;
            smhi += *(const f32x4*)&sthi[i11] * w11v;
        } else {
            uint4 qq[4];
            qq[0] = *(const uint4*)(gb + ((size_t)cy0 * PD + cx0) * C2);
            qq[1] = *(const uint4*)(gb + ((size_t)cy0 * PD + cx1) * C2);
            qq[2] = *(const uint4*)(gb + ((size_t)cy1 * PD + cx0) * C2);
            qq[3] = *(const uint4*)(gb + ((size_t)cy1 * PD + cx1) * C2);
            float wq[4] = {w00, w01, w10, w11};
            #pragma unroll
            for (int c = 0; c < 4; ++c) {
                unsigned uu[4] = {qq[c].x, qq[c].y, qq[c].z, qq[c].w};
                f32x4 lo, hi;
                lo[0] = __uint_as_float(uu[0] << 16); lo[1] = __uint_as_float(uu[0] & 0xffff0000u);
                lo[2] = __uint_as_float(uu[1] << 16); lo[3] = __uint_as_float(uu[1] & 0xffff0000u);
                hi[0] = __uint_as_float(uu[2] << 16); hi[1] = __uint_as_float(uu[2] & 0xffff0000u);
                hi[2] = __uint_as_float(uu[3] << 16); hi[3] = __uint_as_float(uu[3] & 0xffff0000u);
                f32x4 wv4 = {wq[c], wq[c], wq[c], wq[c]};
                smlo += lo * wv4;
                smhi += hi * wv4;
            }
        }

        union { bf16x8 v; unsigned u[4]; } af;
        asm volatile("v_cvt_pk_bf16_f32 %0, %1, %2" : "=v"(af.u[0]) : "v"(smlo[0]), "v"(smlo[1]));
        asm volatile("v_cvt_pk_bf16_f32 %0, %1, %2" : "=v"(af.u[1]) : "v"(smlo[2]), "v"(smlo[3]));
        asm volatile("v_cvt_pk_bf16_f32 %0, %1, %2" : "=v"(af.u[2]) : "v"(smhi[0]), "v"(smhi[1]));
        asm volatile("v_cvt_pk_bf16_f32 %0, %1, %2" : "=v"(af.u[3]) : "v"(smhi[2]), "v"(smhi[3]));

        bf16x8 bf0 = *(const bf16x8*)(wg + (size_t)t * 2 * 64 * 8);
        bf16x8 bf1 = *(const bf16x8*)(wg + (size_t)t * 2 * 64 * 8 + 64 * 8);
        acc0 = __builtin_amdgcn_mfma_f32_16x16x32_bf16(af.v, bf0, acc0, 0, 0, 0);
        acc1 = __builtin_amdgcn_mfma_f32_16x16x32_bf16(af.v, bf1, acc1, 0, 0, 0);
    }

    {
        const int oc = g * CG + l15;
        const float bias = db[oc];
        float4 v;
        v.x = acc0[0] + bias; v.y = acc0[1] + bias;
        v.z = acc0[2] + bias; v.w = acc0[3] + bias;
        *(float4*)(out + ((size_t)b * CIN + oc) * HW + p0 + lk * 4) = v;
    }
    {
        const int oc = g * CG + 16 + l15;
        const float bias = db[oc];
        float4 v;
        v.x = acc1[0] + bias; v.y = acc1[1] + bias;
        v.z = acc1[2] + bias; v.w = acc1[3] + bias;
        *(float4*)(out + ((size_t)b * CIN + oc) * HW + p0 + lk * 4) = v;
    }
}

extern "C" void kernel_launch(void* const* d_in, const int* in_sizes, int n_in,
                              void* d_out, int out_size, void* d_ws, size_t ws_size,
                              hipStream_t stream) {
    const float* rgb     = (const float*)d_in[0];
    const float* thermal = (const float*)d_in[1];
    const float* w1      = (const float*)d_in[2];
    const float* b1      = (const float*)d_in[3];
    const float* w2      = (const float*)d_in[4];
    const float* b2      = (const float*)d_in[5];
    const float* dw      = (const float*)d_in[6];
    const float* db      = (const float*)d_in[7];
    const float* osc     = (const float*)d_in[8];

    char* w = (char*)d_ws;
    unsigned short* rgbcp = (unsigned short*)w;  w += (size_t)BB * PP * C2 * 2;
    unsigned short* hdnp  = (unsigned short*)w;  w += (size_t)BB * PP * MID * 2;
    float*          offs  = (float*)w;           w += (size_t)BB * OFFC * HW * 4;
    unsigned short* w1F   = (unsigned short*)w;  w += (size_t)147456 * 2;
    unsigned short* w2F   = (unsigned short*)w;  w += (size_t)46080 * 2;
    unsigned short* dwF   = (unsigned short*)w;  w += (size_t)36864 * 2;
    float* out = (float*)d_out;

    prep_kernel<<<dim3(1098), 512, 0, stream>>>(w1, w2, dw, rgb, thermal,
                                                w1F, w2F, dwF, rgbcp, hdnp);
    conv1_mfma<<<dim3(BB * HH), 256, 0, stream>>>(rgbcp, w1F, b1, hdnp);
    conv2_mfma<<<dim3(BB * HH), 320, 0, stream>>>(hdnp, w2F, b2, osc, offs);
    deform_kernel<<<dim3(BB * 40 * NG), 640, 0, stream>>>(rgbcp, offs, dwF, db, out);
}

// Round 15
// 99.084 us; speedup vs baseline: 1.0990x; 1.0990x over previous
//
#include <hip/hip_runtime.h>

#define HH 80
#define WW 80
#define BB 8
#define CIN 128
#define C2 256
#define MID 64
#define OFFC 72
#define NG 4
#define CG 32
#define HW (HH * WW)
#define PD 82           // padded spatial dim
#define PP (PD * PD)    // padded pixels per image
#define STP 72          // conv LDS px stride in channels
#define QSTRIDE 493     // deform LDS plane stride in 16B units

typedef short bf16x8 __attribute__((ext_vector_type(8)));
typedef float f32x4  __attribute__((ext_vector_type(4)));

static __device__ __forceinline__ unsigned short f2bf(float f) {
    union { float f; unsigned u; } v; v.f = f;
    unsigned r = v.u + 0x7fffu + ((v.u >> 16) & 1u);   // RNE
    return (unsigned short)(r >> 16);
}

// ---------------- prep: weight packs + borders + rgbc pack (one kernel) -------
__global__ __launch_bounds__(512) void prep_kernel(
    const float* __restrict__ w1, const float* __restrict__ w2,
    const float* __restrict__ dw, const float* __restrict__ rgb,
    const float* __restrict__ thermal,
    unsigned short* __restrict__ w1F, unsigned short* __restrict__ w2F,
    unsigned short* __restrict__ dwF,
    unsigned short* __restrict__ rgbcp, unsigned short* __restrict__ hdnp)
{
    if (blockIdx.x < 450) {
        int idx = blockIdx.x * 512 + threadIdx.x;
        if (idx < 147456) {
            int e  = idx & 7;
            int t1 = idx >> 3;  int l  = t1 & 63;
            int t2 = t1 >> 6;   int cb = t2 & 1;
            int t3 = t2 >> 1;   int tap = t3 % 9;
            int t4 = t3 / 9;    int cc = t4 & 3;  int nf = t4 >> 2;
            int oc = nf * 16 + (l & 15);
            int ic = cc * 64 + cb * 32 + (l >> 4) * 8 + e;
            w1F[idx] = f2bf(w1[((size_t)oc * C2 + ic) * 9 + tap]);
        } else if (idx < 193536) {
            int i2 = idx - 147456;
            int e  = i2 & 7;
            int t1 = i2 >> 3;  int l  = t1 & 63;
            int t2 = t1 >> 6;  int cb = t2 & 1;
            int t3 = t2 >> 1;  int tap = t3 % 9;
            int nf = t3 / 9;
            int oc = nf * 16 + (l & 15);
            int ic = cb * 32 + (l >> 4) * 8 + e;
            float v = (oc < OFFC) ? w2[((size_t)oc * MID + ic) * 9 + tap] : 0.f;
            w2F[i2] = f2bf(v);
        } else {
            int i3 = idx - 193536;
            int e   = i3 & 7;
            int l   = (i3 >> 3) & 63;
            int ocb = (i3 >> 9) & 1;
            int gt  = i3 >> 10;
            int tap = gt % 9, g = gt / 9;
            int oc = ocb * 16 + (l & 15);
            int c  = (l >> 4) * 8 + e;
            dwF[i3] = f2bf(dw[((size_t)(g * CG + oc) * CG + c) * 9 + tap]);
        }
    } else if (blockIdx.x < 458) {
        int idx = (blockIdx.x - 450) * 512 + threadIdx.x;
        if (idx >= BB * 324) return;
        int b = idx / 324, e = idx - (idx / 324) * 324;
        int y, x;
        if (e < 82)       { y = 0;  x = e; }
        else if (e < 164) { y = 81; x = e - 82; }
        else if (e < 244) { y = e - 164 + 1; x = 0; }
        else              { y = e - 244 + 1; x = 81; }
        size_t pos = (size_t)b * PP + y * PD + x;
        uint4 z = {0, 0, 0, 0};
        uint4* r = (uint4*)(rgbcp + pos * C2);
        #pragma unroll
        for (int i = 0; i < 32; ++i) r[i] = z;
        uint4* h = (uint4*)(hdnp + pos * MID);
        #pragma unroll
        for (int i = 0; i < 8; ++i) h[i] = z;
    } else {
        const int pb = blockIdx.x - 458;      // 0..639
        const int b = pb & 7, y = pb >> 3;
        __shared__ unsigned tile[128 * 84];   // [ch-pair][px], 43 KB

        for (int e = threadIdx.x; e < 128 * 20; e += 512) {
            int c2 = e / 20, p4 = e - c2 * 20;
            int ch0 = 2 * c2;
            const float* srcA = (ch0 < CIN)
                ? rgb     + ((size_t)(b * CIN + ch0)       * HH + y) * WW
                : thermal + ((size_t)(b * CIN + ch0 - CIN) * HH + y) * WW;
            float4 a0 = *(const float4*)(srcA + p4 * 4);
            float4 a1 = *(const float4*)(srcA + HW + p4 * 4);
            unsigned w0 = f2bf(a0.x) | ((unsigned)f2bf(a1.x) << 16);
            unsigned w1r = f2bf(a0.y) | ((unsigned)f2bf(a1.y) << 16);
            unsigned w2r = f2bf(a0.z) | ((unsigned)f2bf(a1.z) << 16);
            unsigned w3 = f2bf(a0.w) | ((unsigned)f2bf(a1.w) << 16);
            uint4 v = {w0, w1r, w2r, w3};
            *(uint4*)&tile[c2 * 84 + p4 * 4] = v;
        }
        __syncthreads();

        for (int e = threadIdx.x; e < 80 * 64; e += 512) {
            int px = e >> 6, c4 = e & 63;
            uint2 v;
            v.x = tile[(2 * c4) * 84 + px];
            v.y = tile[(2 * c4 + 1) * 84 + px];
            *(uint2*)(rgbcp + ((size_t)b * PP + (size_t)(y + 1) * PD + px + 1) * C2 + c4 * 4) = v;
        }
    }
}

// ---------------- conv1: implicit GEMM, LDS-staged A, fragment-packed B -------
__global__ __launch_bounds__(256) void conv1_mfma(
    const unsigned short* __restrict__ rgbcp, const unsigned short* __restrict__ w1F,
    const float* __restrict__ b1, unsigned short* __restrict__ hdnp)
{
    const int by = blockIdx.x;
    const int b = by & 7, y = by >> 3;
    const int tid = threadIdx.x;
    const int nf = tid >> 6;
    const int l = tid & 63, l15 = l & 15, lk = l >> 4;

    __shared__ __align__(16) unsigned short st[3 * 82 * STP];   // 35.4 KB

    f32x4 acc[5];
    #pragma unroll
    for (int i = 0; i < 5; ++i) acc[i] = (f32x4){0.f, 0.f, 0.f, 0.f};

    const size_t rowbase = (size_t)b * PP + (size_t)y * PD;

    for (int cc = 0; cc < 4; ++cc) {
        __syncthreads();
        for (int e = tid; e < 3 * 82 * 8; e += 256) {
            int r   = e / 656;
            int rem = e - r * 656;
            int px  = rem >> 3;
            int c8  = rem & 7;
            const uint4 v = *(const uint4*)(rgbcp + (rowbase + (size_t)r * PD + px) * C2 + cc * 64 + c8 * 8);
            *(uint4*)&st[(r * 82 + px) * STP + c8 * 8] = v;
        }
        __syncthreads();

        const unsigned short* bw = w1F + (((size_t)(nf * 4 + cc) * 9) * 2 * 64) * 8;
        #pragma unroll
        for (int tap = 0; tap < 9; ++tap) {
            const int ky = tap / 3, kx = tap - ky * 3;
            #pragma unroll
            for (int cb = 0; cb < 2; ++cb) {
                bf16x8 bf = *(const bf16x8*)(bw + ((size_t)(tap * 2 + cb) * 64 + l) * 8);
                #pragma unroll
                for (int mf = 0; mf < 5; ++mf) {
                    bf16x8 af = *(const bf16x8*)&st[(ky * 82 + mf * 16 + l15 + kx) * STP + cb * 32 + lk * 8];
                    acc[mf] = __builtin_amdgcn_mfma_f32_16x16x32_bf16(af, bf, acc[mf], 0, 0, 0);
                }
            }
        }
    }

    const int oc = nf * 16 + l15;
    const float bias = b1[oc];
    unsigned short* ob = hdnp + ((size_t)b * PP + (size_t)(y + 1) * PD + 1) * MID + oc;
    #pragma unroll
    for (int mf = 0; mf < 5; ++mf)
        #pragma unroll
        for (int r = 0; r < 4; ++r) {
            float v = acc[mf][r] + bias;
            v = v > 0.f ? v : 0.f;
            ob[(size_t)(mf * 16 + lk * 4 + r) * MID] = f2bf(v);
        }
}

// ---------------- conv2: implicit GEMM, LDS-staged A, fragment-packed B -------
__global__ __launch_bounds__(320) void conv2_mfma(
    const unsigned short* __restrict__ hdnp, const unsigned short* __restrict__ w2F,
    const float* __restrict__ b2, const float* __restrict__ scale_p,
    float* __restrict__ offs)
{
    const int by = blockIdx.x;
    const int b = by & 7, y = by >> 3;
    const int tid = threadIdx.x;
    const int nf = tid / 64;
    const int l = tid & 63, l15 = l & 15, lk = l >> 4;

    __shared__ __align__(16) unsigned short st[3 * 82 * STP];

    f32x4 acc[5];
    #pragma unroll
    for (int i = 0; i < 5; ++i) acc[i] = (f32x4){0.f, 0.f, 0.f, 0.f};

    const size_t rowbase = (size_t)b * PP + (size_t)y * PD;

    for (int e = tid; e < 3 * 82 * 8; e += 320) {
        int r   = e / 656;
        int rem = e - r * 656;
        int px  = rem >> 3;
        int c8  = rem & 7;
        const uint4 v = *(const uint4*)(hdnp + (rowbase + (size_t)r * PD + px) * MID + c8 * 8);
        *(uint4*)&st[(r * 82 + px) * STP + c8 * 8] = v;
    }
    __syncthreads();

    const unsigned short* bw = w2F + ((size_t)nf * 9 * 2 * 64) * 8;
    #pragma unroll
    for (int tap = 0; tap < 9; ++tap) {
        const int ky = tap / 3, kx = tap - ky * 3;
        #pragma unroll
        for (int cb = 0; cb < 2; ++cb) {
            bf16x8 bf = *(const bf16x8*)(bw + ((size_t)(tap * 2 + cb) * 64 + l) * 8);
            #pragma unroll
            for (int mf = 0; mf < 5; ++mf) {
                bf16x8 af = *(const bf16x8*)&st[(ky * 82 + mf * 16 + l15 + kx) * STP + cb * 32 + lk * 8];
                acc[mf] = __builtin_amdgcn_mfma_f32_16x16x32_bf16(af, bf, acc[mf], 0, 0, 0);
            }
        }
    }

    const int oc = nf * 16 + l15;
    if (oc < OFFC) {
        const float scale = scale_p[0];
        const float bias = b2[oc];
        float* ob = offs + ((size_t)b * OFFC + oc) * HW + y * WW;
        #pragma unroll
        for (int mf = 0; mf < 5; ++mf) {
            float4 v;
            v.x = (acc[mf][0] + bias) * scale;
            v.y = (acc[mf][1] + bias) * scale;
            v.z = (acc[mf][2] + bias) * scale;
            v.w = (acc[mf][3] + bias) * scale;
            *(float4*)(ob + mf * 16 + lk * 4) = v;
        }
    }
}

// ---------------- deformable conv 3x3: fp32 LDS window + pk-fma bilinear ------
__global__ __launch_bounds__(640) void deform_kernel(
    const unsigned short* __restrict__ rgbcp, const float* __restrict__ offs,
    const unsigned short* __restrict__ dwF, const float* __restrict__ db,
    float* __restrict__ out)
{
    const int b = blockIdx.x & 7;
    const int rem = blockIdx.x >> 3;      // 0..159 (y2 inner, g outer)
    const int y2 = rem % 40;
    const int g  = rem / 40;
    const int wv64 = threadIdx.x >> 6;    // 0..9
    const int h  = (wv64 >= 5) ? 1 : 0;   // row within pair
    const int wv = wv64 - h * 5;          // x-tile 0..4
    const int l = threadIdx.x & 63, l15 = l & 15, lk = l >> 4;

    const int y0 = y2 * 2;
    const int y  = y0 + h;
    const int x  = wv * 16 + l15;
    const int p  = y * WW + x;
    const int p0 = y * WW + wv * 16;
    const int r0 = min(max(y0 - 1, 0), PD - 6);    // staged padded rows r0..r0+5

    __shared__ __align__(16) float st[8 * QSTRIDE * 4];   // 63,104 B

    const unsigned short* gsrc = rgbcp + ((size_t)b * PP + (size_t)r0 * PD) * C2 + g * CG;
    for (int e = threadIdx.x; e < 6 * 82 * 4; e += 640) {
        int pix = e >> 2;
        int c8  = e & 3;
        int r   = pix / 82, px = pix - r * 82;
        uint4 v = *(const uint4*)(gsrc + ((size_t)r * PD + px) * C2 + c8 * 8);
        unsigned uu[4] = {v.x, v.y, v.z, v.w};
        float4 lo, hi;
        lo.x = __uint_as_float(uu[0] << 16); lo.y = __uint_as_float(uu[0] & 0xffff0000u);
        lo.z = __uint_as_float(uu[1] << 16); lo.w = __uint_as_float(uu[1] & 0xffff0000u);
        hi.x = __uint_as_float(uu[2] << 16); hi.y = __uint_as_float(uu[2] & 0xffff0000u);
        hi.z = __uint_as_float(uu[3] << 16); hi.w = __uint_as_float(uu[3] & 0xffff0000u);
        *(float4*)&st[((2 * c8)     * QSTRIDE + pix) * 4] = lo;
        *(float4*)&st[((2 * c8 + 1) * QSTRIDE + pix) * 4] = hi;
    }
    __syncthreads();

    const float* ob = offs + ((size_t)b * OFFC + g * 18) * HW + p;
    float sy[9], sx[9];
    #pragma unroll
    for (int t = 0; t < 9; ++t) {
        float offy = ob[(size_t)(2 * t) * HW];
        float offx = ob[(size_t)(2 * t + 1) * HW];
        sy[t] = (float)(y + t / 3 - 1) + offy;
        sx[t] = (float)(x + t % 3 - 1) + offx;
    }

    f32x4 acc0 = (f32x4){0.f, 0.f, 0.f, 0.f};
    f32x4 acc1 = (f32x4){0.f, 0.f, 0.f, 0.f};
    const unsigned short* gb = rgbcp + (size_t)b * PP * C2 + g * CG + lk * 8;
    const unsigned short* wg = dwF + (size_t)g * 9 * 2 * 64 * 8 + (size_t)l * 8;
    const float* stlo = &st[(2 * lk) * QSTRIDE * 4];
    const float* sthi = &st[(2 * lk + 1) * QSTRIDE * 4];

    #pragma unroll
    for (int t = 0; t < 9; ++t) {
        float fy = floorf(sy[t]), fx = floorf(sx[t]);
        int iy = (int)fy, ix = (int)fx;
        float wy = sy[t] - fy, wx = sx[t] - fx;

        float my0 = ((unsigned)iy       < HH) ? 1.f : 0.f;
        float my1 = ((unsigned)(iy + 1) < HH) ? 1.f : 0.f;
        float mx0 = ((unsigned)ix       < WW) ? 1.f : 0.f;
        float mx1 = ((unsigned)(ix + 1) < WW) ? 1.f : 0.f;
        float w00 = (1.f - wy) * (1.f - wx) * my0 * mx0;
        float w01 = (1.f - wy) * wx         * my0 * mx1;
        float w10 = wy * (1.f - wx)         * my1 * mx0;
        float w11 = wy * wx                 * my1 * mx1;

        int cy0 = min(max(iy, 0), HH - 1) + 1;
        int cy1 = min(max(iy + 1, 0), HH - 1) + 1;
        int cx0 = min(max(ix, 0), WW - 1) + 1;
        int cx1 = min(max(ix + 1, 0), WW - 1) + 1;

        f32x4 smlo = (f32x4){0.f, 0.f, 0.f, 0.f};
        f32x4 smhi = (f32x4){0.f, 0.f, 0.f, 0.f};

        if (cy0 >= r0 && cy1 <= r0 + 5) {
            const int i00 = ((cy0 - r0) * 82 + cx0) * 4;
            const int i01 = ((cy0 - r0) * 82 + cx1) * 4;
            const int i10 = ((cy1 - r0) * 82 + cx0) * 4;
            const int i11 = ((cy1 - r0) * 82 + cx1) * 4;
            f32x4 w00v = {w00, w00, w00, w00};
            f32x4 w01v = {w01, w01, w01, w01};
            f32x4 w10v = {w10, w10, w10, w10};
            f32x4 w11v = {w11, w11, w11, w11};
            smlo += *(const f32x4*)&stlo[i00] * w00v;
            smhi += *(const f32x4*)&sthi[i00] * w00v;
            smlo += *(const f32x4*)&stlo[i01] * w01v;
            smhi += *(const f32x4*)&sthi[i01] * w01v;
            smlo += *(const f32x4*)&stlo[i10] * w10v;
            smhi += *(const f32x4*)&sthi[i10] * w10v;
            smlo += *(const f32x4*)&stlo[i11] * w11v;
            smhi += *(const f32x4*)&sthi[i11] * w11v;
        } else {
            uint4 qq[4];
            qq[0] = *(const uint4*)(gb + ((size_t)cy0 * PD + cx0) * C2);
            qq[1] = *(const uint4*)(gb + ((size_t)cy0 * PD + cx1) * C2);
            qq[2] = *(const uint4*)(gb + ((size_t)cy1 * PD + cx0) * C2);
            qq[3] = *(const uint4*)(gb + ((size_t)cy1 * PD + cx1) * C2);
            float wq[4] = {w00, w01, w10, w11};
            #pragma unroll
            for (int c = 0; c < 4; ++c) {
                unsigned uu[4] = {qq[c].x, qq[c].y, qq[c].z, qq[c].w};
                f32x4 lo, hi;
                lo[0] = __uint_as_float(uu[0] << 16); lo[1] = __uint_as_float(uu[0] & 0xffff0000u);
                lo[2] = __uint_as_float(uu[1] << 16); lo[3] = __uint_as_float(uu[1] & 0xffff0000u);
                hi[0] = __uint_as_float(uu[2] << 16); hi[1] = __uint_as_float(uu[2] & 0xffff0000u);
                hi[2] = __uint_as_float(uu[3] << 16); hi[3] = __uint_as_float(uu[3] & 0xffff0000u);
                f32x4 wv4 = {wq[c], wq[c], wq[c], wq[c]};
                smlo += lo * wv4;
                smhi += hi * wv4;
            }
        }

        union { bf16x8 v; unsigned u[4]; } af;
        asm volatile("v_cvt_pk_bf16_f32 %0, %1, %2" : "=v"(af.u[0]) : "v"(smlo[0]), "v"(smlo[1]));
        asm volatile("v_cvt_pk_bf16_f32 %0, %1, %2" : "=v"(af.u[1]) : "v"(smlo[2]), "v"(smlo[3]));
        asm volatile("v_cvt_pk_bf16_f32 %0, %1, %2" : "=v"(af.u[2]) : "v"(smhi[0]), "v"(smhi[1]));
        asm volatile("v_cvt_pk_bf16_f32 %0, %1, %2" : "=v"(af.u[3]) : "v"(smhi[2]), "v"(smhi[3]));

        bf16x8 bf0 = *(const bf16x8*)(wg + (size_t)t * 2 * 64 * 8);
        bf16x8 bf1 = *(const bf16x8*)(wg + (size_t)t * 2 * 64 * 8 + 64 * 8);
        acc0 = __builtin_amdgcn_mfma_f32_16x16x32_bf16(af.v, bf0, acc0, 0, 0, 0);
        acc1 = __builtin_amdgcn_mfma_f32_16x16x32_bf16(af.v, bf1, acc1, 0, 0, 0);
    }

    {
        const int oc = g * CG + l15;
        const float bias = db[oc];
        float4 v;
        v.x = acc0[0] + bias; v.y = acc0[1] + bias;
        v.z = acc0[2] + bias; v.w = acc0[3] + bias;
        *(float4*)(out + ((size_t)b * CIN + oc) * HW + p0 + lk * 4) = v;
    }
    {
        const int oc = g * CG + 16 + l15;
        const float bias = db[oc];
        float4 v;
        v.x = acc1[0] + bias; v.y = acc1[1] + bias;
        v.z = acc1[2] + bias; v.w = acc1[3] + bias;
        *(float4*)(out + ((size_t)b * CIN + oc) * HW + p0 + lk * 4) = v;
    }
}

extern "C" void kernel_launch(void* const* d_in, const int* in_sizes, int n_in,
                              void* d_out, int out_size, void* d_ws, size_t ws_size,
                              hipStream_t stream) {
    const float* rgb     = (const float*)d_in[0];
    const float* thermal = (const float*)d_in[1];
    const float* w1      = (const float*)d_in[2];
    const float* b1      = (const float*)d_in[3];
    const float* w2      = (const float*)d_in[4];
    const float* b2      = (const float*)d_in[5];
    const float* dw      = (const float*)d_in[6];
    const float* db      = (const float*)d_in[7];
    const float* osc     = (const float*)d_in[8];

    char* w = (char*)d_ws;
    unsigned short* rgbcp = (unsigned short*)w;  w += (size_t)BB * PP * C2 * 2;
    unsigned short* hdnp  = (unsigned short*)w;  w += (size_t)BB * PP * MID * 2;
    float*          offs  = (float*)w;           w += (size_t)BB * OFFC * HW * 4;
    unsigned short* w1F   = (unsigned short*)w;  w += (size_t)147456 * 2;
    unsigned short* w2F   = (unsigned short*)w;  w += (size_t)46080 * 2;
    unsigned short* dwF   = (unsigned short*)w;  w += (size_t)36864 * 2;
    float* out = (float*)d_out;

    prep_kernel<<<dim3(1098), 512, 0, stream>>>(w1, w2, dw, rgb, thermal,
                                                w1F, w2F, dwF, rgbcp, hdnp);
    conv1_mfma<<<dim3(BB * HH), 256, 0, stream>>>(rgbcp, w1F, b1, hdnp);
    conv2_mfma<<<dim3(BB * HH), 320, 0, stream>>>(hdnp, w2F, b2, osc, offs);
    deform_kernel<<<dim3(BB * 40 * NG), 640, 0, stream>>>(rgbcp, offs, dwF, db, out);
}